// Round 1
// baseline (390.583 us; speedup 1.0000x reference)
//
#include <hip/hip_runtime.h>

// NewNormalizationUnit: SNN-gate priority encoder + shift encoder + exponent
// adjuster + barrel shifter, reduced to integer bit logic.
//
// Input : P [B,8] float32, values in {0.0, 1.0}  (little-endian bits)
// Output (concat flat, float32):
//   p_norm   [B,8]  at out + 0
//   exp_adj  [B,5]  at out + B*8
//   sticky   [B,1]  at out + B*13
//   overflow [B,1]  at out + B*14
//   shift    [B,3]  at out + B*15
//
// Semantics (verified against reference dataflow):
//   m   = bitmask of row (bit i = P[i] >= 0.5)
//   k   = index of highest set bit of m (one-hot "valid" v[k])
//   shift = m ? 7-k : 0           (s0=bit0, s1=bit1, s2=bit2 of shift)
//   pre = m >> 1                  (drop LSB, append 0 at top)
//   p_norm = (pre << shift) & 0xFF
//   is_zero = (m == 0)
//   e0 = (k&1) | is_zero          (v7|v5|v3|v1|is_zero)
//   e1 = !is_zero & !(k&2)        (v5|v4|v1|v0)
//   e2 = !is_zero & (2<=k<=5)     (v5|v4|v3|v2)
//   e3 = e4 = (k<=5) | is_zero    (v5..v0 | is_zero; k=0 when m==0 so just k<=5)
//   sticky = bit0(m), overflow = bit7(m)

__global__ __launch_bounds__(256) void snn_norm_kernel(
    const float* __restrict__ P, float* __restrict__ out, unsigned B)
{
    float* __restrict__ p_norm   = out;
    float* __restrict__ exp_adj  = out + (size_t)B * 8;
    float* __restrict__ sticky   = out + (size_t)B * 13;
    float* __restrict__ overflow = out + (size_t)B * 14;
    float* __restrict__ shamt    = out + (size_t)B * 15;

    const unsigned stride = gridDim.x * blockDim.x;
    for (unsigned r = blockIdx.x * blockDim.x + threadIdx.x; r < B; r += stride) {
        const float4 a = reinterpret_cast<const float4*>(P)[(size_t)r * 2];
        const float4 b = reinterpret_cast<const float4*>(P)[(size_t)r * 2 + 1];

        unsigned m = 0;
        m |= (a.x >= 0.5f) ? 1u   : 0u;
        m |= (a.y >= 0.5f) ? 2u   : 0u;
        m |= (a.z >= 0.5f) ? 4u   : 0u;
        m |= (a.w >= 0.5f) ? 8u   : 0u;
        m |= (b.x >= 0.5f) ? 16u  : 0u;
        m |= (b.y >= 0.5f) ? 32u  : 0u;
        m |= (b.z >= 0.5f) ? 64u  : 0u;
        m |= (b.w >= 0.5f) ? 128u : 0u;

        // k = highest set bit of m (0 when m==0 via m|1); branchless.
        const int k = 31 - __clz((int)(m | 1u));
        const bool nz = (m != 0u);

        const unsigned shift = nz ? (7u - (unsigned)k) : 0u;
        const unsigned pn = ((m >> 1) << shift) & 0xFFu;

        const unsigned e0 = (unsigned)(k & 1) | (nz ? 0u : 1u);
        const unsigned e1 = (nz && ((k & 2) == 0)) ? 1u : 0u;
        const unsigned e2 = (nz && (k >= 2) && (k <= 5)) ? 1u : 0u;
        const unsigned e3 = (k <= 5) ? 1u : 0u;   // k=0 when m==0 -> 1 (is_zero path)

        // p_norm: 8 floats, two coalesced float4 stores
        float4 o0, o1;
        o0.x = (float)( pn       & 1u);
        o0.y = (float)((pn >> 1) & 1u);
        o0.z = (float)((pn >> 2) & 1u);
        o0.w = (float)((pn >> 3) & 1u);
        o1.x = (float)((pn >> 4) & 1u);
        o1.y = (float)((pn >> 5) & 1u);
        o1.z = (float)((pn >> 6) & 1u);
        o1.w = (float)((pn >> 7) & 1u);
        reinterpret_cast<float4*>(p_norm)[(size_t)r * 2]     = o0;
        reinterpret_cast<float4*>(p_norm)[(size_t)r * 2 + 1] = o1;

        float* e = exp_adj + (size_t)r * 5;
        e[0] = (float)e0;
        e[1] = (float)e1;
        e[2] = (float)e2;
        e[3] = (float)e3;
        e[4] = (float)e3;

        sticky[r]   = (float)(m & 1u);
        overflow[r] = (float)(m >> 7);

        float* s = shamt + (size_t)r * 3;
        s[0] = (float)( shift       & 1u);
        s[1] = (float)((shift >> 1) & 1u);
        s[2] = (float)((shift >> 2) & 1u);
    }
}

extern "C" void kernel_launch(void* const* d_in, const int* in_sizes, int n_in,
                              void* d_out, int out_size, void* d_ws, size_t ws_size,
                              hipStream_t stream) {
    const float* P = (const float*)d_in[0];
    float* out = (float*)d_out;
    const unsigned B = (unsigned)(in_sizes[0] / 8);

    const int threads = 256;
    const int blocks = 2048;  // grid-stride: 8 rows/thread at B=4M
    snn_norm_kernel<<<blocks, threads, 0, stream>>>(P, out, B);
}

// Round 4
// 385.205 us; speedup vs baseline: 1.0140x; 1.0140x over previous
//
#include <hip/hip_runtime.h>

// NewNormalizationUnit: SNN-gate priority encoder + shift encoder + exponent
// adjuster + barrel shifter, reduced to integer bit logic.
//
// Input : P [B,8] float32 in {0.0,1.0} (little-endian bits)
// Output (concat flat, float32):
//   p_norm [B,8] @0 | exp_adj [B,5] @B*8 | sticky [B,1] @B*13 |
//   overflow [B,1] @B*14 | shift [B,3] @B*15
//
// Round 2 kernel (3rd submit; two broker timeouts): LDS-staged stores.
// Round 1 was store-transaction-bound (stride-5/-3 scalar stores -> ~2.6x
// request amplification). Each block handles a 256-row tile: compute
// per-row, stage p_norm/exp/shamt in LDS, drain with packed float4 stores.
//
// Bit semantics (identical to round 1, absmax=0 verified):
//   m = bitmask(P[r] >= 0.5); k = msb(m|1); nz = m!=0
//   shift = nz ? 7-k : 0 ; p_norm = ((m>>1) << shift) & 0xFF
//   e0=(k&1)|!nz ; e1=nz&!(k&2) ; e2=nz&(2<=k<=5) ; e3=e4=(k<=5)
//   sticky=m&1 ; overflow=m>>7

#define TILE 256

__global__ __launch_bounds__(256) void snn_norm_kernel(
    const float* __restrict__ P, float* __restrict__ out, unsigned B)
{
    float* __restrict__ p_norm   = out;
    float* __restrict__ exp_adj  = out + (size_t)B * 8;
    float* __restrict__ sticky   = out + (size_t)B * 13;
    float* __restrict__ overflow = out + (size_t)B * 14;
    float* __restrict__ shamt    = out + (size_t)B * 15;

    __shared__ float lds_pn[TILE * 8];   // 8 KiB
    __shared__ float lds_e [TILE * 5];   // 5 KiB
    __shared__ float lds_sh[TILE * 3];   // 3 KiB

    const unsigned tid = threadIdx.x;
    const size_t tileRow = (size_t)blockIdx.x * TILE;
    const size_t r = tileRow + tid;

    // ---- stage phase: one row per thread ----
    if (r < B) {
        const float4 a = reinterpret_cast<const float4*>(P)[r * 2];
        const float4 b = reinterpret_cast<const float4*>(P)[r * 2 + 1];

        unsigned m = 0;
        m |= (a.x >= 0.5f) ? 1u   : 0u;
        m |= (a.y >= 0.5f) ? 2u   : 0u;
        m |= (a.z >= 0.5f) ? 4u   : 0u;
        m |= (a.w >= 0.5f) ? 8u   : 0u;
        m |= (b.x >= 0.5f) ? 16u  : 0u;
        m |= (b.y >= 0.5f) ? 32u  : 0u;
        m |= (b.z >= 0.5f) ? 64u  : 0u;
        m |= (b.w >= 0.5f) ? 128u : 0u;

        const int k = 31 - __clz((int)(m | 1u));
        const bool nz = (m != 0u);

        const unsigned shift = nz ? (7u - (unsigned)k) : 0u;
        const unsigned pn = ((m >> 1) << shift) & 0xFFu;

        const unsigned e0 = (unsigned)(k & 1) | (nz ? 0u : 1u);
        const unsigned e1 = (nz && ((k & 2) == 0)) ? 1u : 0u;
        const unsigned e2 = (nz && (k >= 2) && (k <= 5)) ? 1u : 0u;
        const unsigned e3 = (k <= 5) ? 1u : 0u;

        float4 o0, o1;
        o0.x = (float)( pn       & 1u);
        o0.y = (float)((pn >> 1) & 1u);
        o0.z = (float)((pn >> 2) & 1u);
        o0.w = (float)((pn >> 3) & 1u);
        o1.x = (float)((pn >> 4) & 1u);
        o1.y = (float)((pn >> 5) & 1u);
        o1.z = (float)((pn >> 6) & 1u);
        o1.w = (float)((pn >> 7) & 1u);
        reinterpret_cast<float4*>(lds_pn)[tid * 2]     = o0;
        reinterpret_cast<float4*>(lds_pn)[tid * 2 + 1] = o1;

        // stride-5 dword LDS writes: gcd(5,32)=1 -> conflict-free
        lds_e[tid * 5 + 0] = (float)e0;
        lds_e[tid * 5 + 1] = (float)e1;
        lds_e[tid * 5 + 2] = (float)e2;
        lds_e[tid * 5 + 3] = (float)e3;
        lds_e[tid * 5 + 4] = (float)e3;

        // stride-3: gcd(3,32)=1 -> conflict-free
        lds_sh[tid * 3 + 0] = (float)( shift       & 1u);
        lds_sh[tid * 3 + 1] = (float)((shift >> 1) & 1u);
        lds_sh[tid * 3 + 2] = (float)((shift >> 2) & 1u);

        // already perfectly coalesced (stride-1 per lane): store direct
        sticky[r]   = (float)(m & 1u);
        overflow[r] = (float)(m >> 7);
    }

    __syncthreads();

    // ---- drain phase: packed float4, lane-contiguous ----
    if (tileRow + TILE <= B) {
        // full tile: all regions 16B-aligned at tile granularity
        float4* __restrict__ pnG = reinterpret_cast<float4*>(p_norm + tileRow * 8);
        const float4* pnL = reinterpret_cast<const float4*>(lds_pn);
        #pragma unroll
        for (int i = 0; i < 2; ++i)                    // 512 f4
            pnG[tid + i * 256] = pnL[tid + i * 256];

        float4* __restrict__ eG = reinterpret_cast<float4*>(exp_adj + tileRow * 5);
        const float4* eL = reinterpret_cast<const float4*>(lds_e);
        for (int i = tid; i < TILE * 5 / 4; i += 256)  // 320 f4
            eG[i] = eL[i];

        float4* __restrict__ sG = reinterpret_cast<float4*>(shamt + tileRow * 3);
        const float4* sL = reinterpret_cast<const float4*>(lds_sh);
        for (int i = tid; i < TILE * 3 / 4; i += 256)  // 192 f4
            sG[i] = sL[i];
    } else {
        // ragged tail: dword-granular drain
        const unsigned rows = (unsigned)(B - tileRow);
        for (unsigned i = tid; i < rows * 8; i += 256)
            p_norm[tileRow * 8 + i] = lds_pn[i];
        for (unsigned i = tid; i < rows * 5; i += 256)
            exp_adj[tileRow * 5 + i] = lds_e[i];
        for (unsigned i = tid; i < rows * 3; i += 256)
            shamt[tileRow * 3 + i] = lds_sh[i];
    }
}

extern "C" void kernel_launch(void* const* d_in, const int* in_sizes, int n_in,
                              void* d_out, int out_size, void* d_ws, size_t ws_size,
                              hipStream_t stream) {
    const float* P = (const float*)d_in[0];
    float* out = (float*)d_out;
    const unsigned B = (unsigned)(in_sizes[0] / 8);

    const int threads = 256;
    const int blocks = (int)((B + TILE - 1) / TILE);   // one 256-row tile per block
    snn_norm_kernel<<<blocks, threads, 0, stream>>>(P, out, B);
}

// Round 9
// 374.615 us; speedup vs baseline: 1.0426x; 1.0283x over previous
//
#include <hip/hip_runtime.h>

// NewNormalizationUnit: SNN-gate priority encoder + shift encoder + exponent
// adjuster + barrel shifter, reduced to integer bit logic.
//
// Input : P [B,8] float32 in {0.0,1.0} (little-endian bits)
// Output (concat flat, float32):
//   p_norm [B,8] @0 | exp_adj [B,5] @B*8 | sticky [B,1] @B*13 |
//   overflow [B,1] @B*14 | shift [B,3] @B*15
//
// Round 3 kernel (5th submit; broker timeouts): LDS-staged structure +
// NONTEMPORAL global accesses. Round 1 (scalar strided stores) == round 2
// (LDS-staged f4 stores) within noise => store transactions not dominant;
// remaining kernel slack attributed to cache write-alloc/pollution on
// streaming data. nt bit on all global loads/stores (data never re-read).
//
// Bit semantics (absmax=0 verified, rounds 1-2):
//   m = bitmask(P[r] >= 0.5); k = msb(m|1); nz = m!=0
//   shift = nz ? 7-k : 0 ; p_norm = ((m>>1) << shift) & 0xFF
//   e0=(k&1)|!nz ; e1=nz&!(k&2) ; e2=nz&(2<=k<=5) ; e3=e4=(k<=5)
//   sticky=m&1 ; overflow=m>>7

#define TILE 256

typedef float f32x4 __attribute__((ext_vector_type(4)));

__global__ __launch_bounds__(256) void snn_norm_kernel(
    const float* __restrict__ P, float* __restrict__ out, unsigned B)
{
    float* __restrict__ p_norm   = out;
    float* __restrict__ exp_adj  = out + (size_t)B * 8;
    float* __restrict__ sticky   = out + (size_t)B * 13;
    float* __restrict__ overflow = out + (size_t)B * 14;
    float* __restrict__ shamt    = out + (size_t)B * 15;

    __shared__ float lds_pn[TILE * 8];   // 8 KiB
    __shared__ float lds_e [TILE * 5];   // 5 KiB
    __shared__ float lds_sh[TILE * 3];   // 3 KiB

    const unsigned tid = threadIdx.x;
    const size_t tileRow = (size_t)blockIdx.x * TILE;
    const size_t r = tileRow + tid;

    // ---- stage phase: one row per thread ----
    if (r < B) {
        const f32x4 a = __builtin_nontemporal_load(
            reinterpret_cast<const f32x4*>(P) + r * 2);
        const f32x4 b = __builtin_nontemporal_load(
            reinterpret_cast<const f32x4*>(P) + r * 2 + 1);

        unsigned m = 0;
        m |= (a.x >= 0.5f) ? 1u   : 0u;
        m |= (a.y >= 0.5f) ? 2u   : 0u;
        m |= (a.z >= 0.5f) ? 4u   : 0u;
        m |= (a.w >= 0.5f) ? 8u   : 0u;
        m |= (b.x >= 0.5f) ? 16u  : 0u;
        m |= (b.y >= 0.5f) ? 32u  : 0u;
        m |= (b.z >= 0.5f) ? 64u  : 0u;
        m |= (b.w >= 0.5f) ? 128u : 0u;

        const int k = 31 - __clz((int)(m | 1u));
        const bool nz = (m != 0u);

        const unsigned shift = nz ? (7u - (unsigned)k) : 0u;
        const unsigned pn = ((m >> 1) << shift) & 0xFFu;

        const unsigned e0 = (unsigned)(k & 1) | (nz ? 0u : 1u);
        const unsigned e1 = (nz && ((k & 2) == 0)) ? 1u : 0u;
        const unsigned e2 = (nz && (k >= 2) && (k <= 5)) ? 1u : 0u;
        const unsigned e3 = (k <= 5) ? 1u : 0u;

        f32x4 o0, o1;
        o0.x = (float)( pn       & 1u);
        o0.y = (float)((pn >> 1) & 1u);
        o0.z = (float)((pn >> 2) & 1u);
        o0.w = (float)((pn >> 3) & 1u);
        o1.x = (float)((pn >> 4) & 1u);
        o1.y = (float)((pn >> 5) & 1u);
        o1.z = (float)((pn >> 6) & 1u);
        o1.w = (float)((pn >> 7) & 1u);
        reinterpret_cast<f32x4*>(lds_pn)[tid * 2]     = o0;
        reinterpret_cast<f32x4*>(lds_pn)[tid * 2 + 1] = o1;

        // stride-5 dword LDS writes: gcd(5,32)=1 -> conflict-free
        lds_e[tid * 5 + 0] = (float)e0;
        lds_e[tid * 5 + 1] = (float)e1;
        lds_e[tid * 5 + 2] = (float)e2;
        lds_e[tid * 5 + 3] = (float)e3;
        lds_e[tid * 5 + 4] = (float)e3;

        // stride-3: gcd(3,32)=1 -> conflict-free
        lds_sh[tid * 3 + 0] = (float)( shift       & 1u);
        lds_sh[tid * 3 + 1] = (float)((shift >> 1) & 1u);
        lds_sh[tid * 3 + 2] = (float)((shift >> 2) & 1u);

        // stride-1 per lane already: direct nt stores
        __builtin_nontemporal_store((float)(m & 1u),  sticky + r);
        __builtin_nontemporal_store((float)(m >> 7),  overflow + r);
    }

    __syncthreads();

    // ---- drain phase: packed float4, lane-contiguous, nontemporal ----
    if (tileRow + TILE <= B) {
        f32x4* __restrict__ pnG = reinterpret_cast<f32x4*>(p_norm + tileRow * 8);
        const f32x4* pnL = reinterpret_cast<const f32x4*>(lds_pn);
        #pragma unroll
        for (int i = 0; i < 2; ++i)                    // 512 f4
            __builtin_nontemporal_store(pnL[tid + i * 256], pnG + tid + i * 256);

        f32x4* __restrict__ eG = reinterpret_cast<f32x4*>(exp_adj + tileRow * 5);
        const f32x4* eL = reinterpret_cast<const f32x4*>(lds_e);
        for (int i = tid; i < TILE * 5 / 4; i += 256)  // 320 f4
            __builtin_nontemporal_store(eL[i], eG + i);

        f32x4* __restrict__ sG = reinterpret_cast<f32x4*>(shamt + tileRow * 3);
        const f32x4* sL = reinterpret_cast<const f32x4*>(lds_sh);
        for (int i = tid; i < TILE * 3 / 4; i += 256)  // 192 f4
            __builtin_nontemporal_store(sL[i], sG + i);
    } else {
        // ragged tail: dword-granular drain
        const unsigned rows = (unsigned)(B - tileRow);
        for (unsigned i = tid; i < rows * 8; i += 256)
            p_norm[tileRow * 8 + i] = lds_pn[i];
        for (unsigned i = tid; i < rows * 5; i += 256)
            exp_adj[tileRow * 5 + i] = lds_e[i];
        for (unsigned i = tid; i < rows * 3; i += 256)
            shamt[tileRow * 3 + i] = lds_sh[i];
    }
}

extern "C" void kernel_launch(void* const* d_in, const int* in_sizes, int n_in,
                              void* d_out, int out_size, void* d_ws, size_t ws_size,
                              hipStream_t stream) {
    const float* P = (const float*)d_in[0];
    float* out = (float*)d_out;
    const unsigned B = (unsigned)(in_sizes[0] / 8);

    const int threads = 256;
    const int blocks = (int)((B + TILE - 1) / TILE);   // one 256-row tile per block
    snn_norm_kernel<<<blocks, threads, 0, stream>>>(P, out, B);
}